// Round 1
// baseline (211.502 us; speedup 1.0000x reference)
//
#include <hip/hip_runtime.h>

// NFLinear equivariant layer, decomposed into closed-form terms.
// out0[a,b,:] = w_ih[a,b,:]@th0[0] + A0C[a,:] + B0[b,:]            (A0C = A0 + C0)
// out1[a,b,:] = Y[a,b,:]@th1[13] + Y[b,a,:]@th1[11] + A1C[a,:] + B1[b,:] + (a==b)*DD1[a,:]
// out2[b,:]   = vectors(b)@th2[...] + scalars                      (written by k_vec)

__global__ void k_rowmean_ih(const float* __restrict__ w, float* __restrict__ rm) {
  __shared__ float4 lds[256];
  int t = threadIdx.x;
  const float4* row = (const float4*)(w + (size_t)blockIdx.x * 8192);
  float4 acc = make_float4(0.f, 0.f, 0.f, 0.f);
  for (int j = t; j < 2048; j += 256) {
    float4 v = row[j];
    acc.x += v.x; acc.y += v.y; acc.z += v.z; acc.w += v.w;
  }
  lds[t] = acc;
  __syncthreads();
  #pragma unroll
  for (int s = 128; s >= 4; s >>= 1) {
    if (t < s) {
      float4 o = lds[t + s], m = lds[t];
      m.x += o.x; m.y += o.y; m.z += o.z; m.w += o.w;
      lds[t] = m;
    }
    __syncthreads();
  }
  if (t < 4) {
    float4 m = lds[t];
    const float s = 1.0f / 512.0f;
    float* dst = rm + blockIdx.x * 16 + t * 4;
    dst[0] = m.x * s; dst[1] = m.y * s; dst[2] = m.z * s; dst[3] = m.w * s;
  }
}

// one block per b: cm_ih[b,:], rm_hh[b,:], cm_hh[b,:], d_hh[b,:]
__global__ void k_colred(const float* __restrict__ wih, const float* __restrict__ whh,
                         float* __restrict__ cm_ih, float* __restrict__ rm_hh,
                         float* __restrict__ cm_hh, float* __restrict__ d_hh) {
  __shared__ float lds[256];
  int t = threadIdx.x, b = blockIdx.x;
  int ci = t & 15, g = t >> 4;

  float acc = 0.f;
  for (int a = g; a < 784; a += 16) acc += wih[(size_t)a * 8192 + b * 16 + ci];
  lds[t] = acc; __syncthreads();
  for (int s = 128; s >= 16; s >>= 1) { if (t < s) lds[t] += lds[t + s]; __syncthreads(); }
  if (t < 16) cm_ih[b * 16 + t] = lds[t] * (1.0f / 784.0f);
  __syncthreads();

  const float* rowp = whh + (size_t)b * 8192;
  acc = 0.f;
  for (int n = t; n < 8192; n += 256) acc += rowp[n];  // 256%16==0 -> t%16 fixed ci
  lds[t] = acc; __syncthreads();
  for (int s = 128; s >= 16; s >>= 1) { if (t < s) lds[t] += lds[t + s]; __syncthreads(); }
  if (t < 16) rm_hh[b * 16 + t] = lds[t] * (1.0f / 512.0f);
  __syncthreads();

  acc = 0.f;
  for (int c = g; c < 512; c += 16) acc += whh[(size_t)c * 8192 + b * 16 + ci];
  lds[t] = acc; __syncthreads();
  for (int s = 128; s >= 16; s >>= 1) { if (t < s) lds[t] += lds[t + s]; __syncthreads(); }
  if (t < 16) {
    cm_hh[b * 16 + t] = lds[t] * (1.0f / 512.0f);
    d_hh[b * 16 + t]  = whh[(size_t)b * 8192 + b * 16 + t];
  }
}

// one block: global means + theta-projected scalar vectors C0, C1, E1, scal2
__global__ void k_scalars(const float* __restrict__ rm_ih, const float* __restrict__ d_hh,
                          const float* __restrict__ rm_hh, const float* __restrict__ bvec,
                          const float* __restrict__ th0, const float* __restrict__ bias0,
                          const float* __restrict__ th1, const float* __restrict__ bias1,
                          const float* __restrict__ th2, const float* __restrict__ bias2,
                          float* __restrict__ sc) {
  __shared__ float lds[256];
  __shared__ float gv[4][16];  // g_ih, dm, g_hh, mv
  int t = threadIdx.x, ci = t & 15, g = t >> 4;

  float acc = 0.f;
  for (int a = g; a < 784; a += 16) acc += rm_ih[a * 16 + ci];
  lds[t] = acc; __syncthreads();
  for (int s = 128; s >= 16; s >>= 1) { if (t < s) lds[t] += lds[t + s]; __syncthreads(); }
  if (t < 16) gv[0][t] = lds[t] * (1.0f / 784.0f);
  __syncthreads();

  acc = 0.f;
  for (int a = g; a < 512; a += 16) acc += d_hh[a * 16 + ci];
  lds[t] = acc; __syncthreads();
  for (int s = 128; s >= 16; s >>= 1) { if (t < s) lds[t] += lds[t + s]; __syncthreads(); }
  if (t < 16) gv[1][t] = lds[t] * (1.0f / 512.0f);
  __syncthreads();

  acc = 0.f;
  for (int a = g; a < 512; a += 16) acc += rm_hh[a * 16 + ci];
  lds[t] = acc; __syncthreads();
  for (int s = 128; s >= 16; s >>= 1) { if (t < s) lds[t] += lds[t + s]; __syncthreads(); }
  if (t < 16) gv[2][t] = lds[t] * (1.0f / 512.0f);
  __syncthreads();

  acc = 0.f;
  for (int a = g; a < 512; a += 16) acc += bvec[a * 16 + ci];
  lds[t] = acc; __syncthreads();
  for (int s = 128; s >= 16; s >>= 1) { if (t < s) lds[t] += lds[t + s]; __syncthreads(); }
  if (t < 16) gv[3][t] = lds[t] * (1.0f / 512.0f);
  __syncthreads();

  if (t < 16) {
    int co = t;
    float c0 = bias0[co], c1 = bias1[co], e1 = 0.f, s2 = bias2[co];
    for (int k = 0; k < 16; k++) {
      float gi = gv[0][k], dmv = gv[1][k], gh = gv[2][k], m = gv[3][k];
      int o = k * 16 + co;
      c0 += gi * th0[3 * 256 + o] + dmv * th0[5 * 256 + o] + gh * th0[8 * 256 + o] + m * th0[10 * 256 + o];
      c1 += gi * th1[4 * 256 + o] + dmv * th1[9 * 256 + o] + gh * th1[19 * 256 + o] + m * th1[24 * 256 + o];
      e1 += gi * th1[2 * 256 + o] + dmv * th1[7 * 256 + o] + gh * th1[16 * 256 + o] + m * th1[22 * 256 + o];
      s2 += gi * th2[1 * 256 + o] + dmv * th2[3 * 256 + o] + gh * th2[6 * 256 + o] + m * th2[8 * 256 + o];
    }
    sc[co] = c0; sc[16 + co] = c1; sc[32 + co] = e1; sc[48 + co] = s2;
  }
}

// per (row i, co): A0C, B0, A1C, B1, DD1 and out2
__global__ void k_vec(const float* __restrict__ rm_ih, const float* __restrict__ cm_ih,
                      const float* __restrict__ rm_hh, const float* __restrict__ cm_hh,
                      const float* __restrict__ d_hh, const float* __restrict__ bvec,
                      const float* __restrict__ th0, const float* __restrict__ th1,
                      const float* __restrict__ th2, const float* __restrict__ sc,
                      float* __restrict__ A0C, float* __restrict__ B0,
                      float* __restrict__ A1C, float* __restrict__ B1,
                      float* __restrict__ DD1, float* __restrict__ out2) {
  int idx = blockIdx.x * 256 + threadIdx.x;
  if (idx >= 784 * 16) return;
  int i = idx >> 4, co = idx & 15;
  float a0 = sc[co];
  for (int k = 0; k < 16; k++) a0 += rm_ih[i * 16 + k] * th0[1 * 256 + k * 16 + co];
  A0C[idx] = a0;
  if (i < 512) {
    float b0a = 0.f, a1 = sc[16 + co], b1a = 0.f, dd = sc[32 + co], o2 = sc[48 + co];
    for (int k = 0; k < 16; k++) {
      float cmi = cm_ih[i * 16 + k], d = d_hh[i * 16 + k], r = rm_hh[i * 16 + k];
      float cm = cm_hh[i * 16 + k], v = bvec[i * 16 + k];
      int o = k * 16 + co;
      b0a += cmi * th0[2 * 256 + o] + d * th0[4 * 256 + o] + r * th0[6 * 256 + o] + cm * th0[7 * 256 + o] + v * th0[9 * 256 + o];
      a1  += cmi * th1[3 * 256 + o] + d * th1[8 * 256 + o] + r * th1[17 * 256 + o] + cm * th1[18 * 256 + o] + v * th1[23 * 256 + o];
      b1a += cmi * th1[1 * 256 + o] + d * th1[6 * 256 + o] + r * th1[12 * 256 + o] + cm * th1[15 * 256 + o] + v * th1[21 * 256 + o];
      dd  += cmi * th1[0 * 256 + o] + d * th1[5 * 256 + o] + r * th1[10 * 256 + o] + cm * th1[14 * 256 + o] + v * th1[20 * 256 + o];
      o2  += cmi * th2[0 * 256 + o] + d * th2[2 * 256 + o] + r * th2[4 * 256 + o] + cm * th2[5 * 256 + o] + v * th2[7 * 256 + o];
    }
    B0[idx] = b0a; A1C[idx] = a1; B1[idx] = b1a; DD1[idx] = dd; out2[idx] = o2;
  }
}

// out0: 4 lanes per (a,b) pair, each owns a co-quad; theta quad hoisted in VGPRs
__global__ __launch_bounds__(256)
void k_out0(const float* __restrict__ w, const float* __restrict__ th0,
            const float* __restrict__ A0C, const float* __restrict__ B0,
            float* __restrict__ out0) {
  int tid = blockIdx.x * 256 + threadIdx.x;
  int q = tid & 3;
  int slot = tid >> 2;
  int nslots = (gridDim.x * 256) >> 2;
  float4 tq[16];
  #pragma unroll
  for (int k = 0; k < 16; k++) tq[k] = *(const float4*)(th0 + k * 16 + q * 4);
  for (int p = slot; p < 784 * 512; p += nslots) {
    const float4* row = (const float4*)(w + (size_t)p * 16);
    float4 r0 = row[0], r1 = row[1], r2 = row[2], r3 = row[3];
    int a = p >> 9, bb = p & 511;
    float4 acc = *(const float4*)(A0C + a * 16 + q * 4);
    float4 b4 = *(const float4*)(B0 + bb * 16 + q * 4);
    acc.x += b4.x; acc.y += b4.y; acc.z += b4.z; acc.w += b4.w;
    float wv[16] = { r0.x, r0.y, r0.z, r0.w, r1.x, r1.y, r1.z, r1.w,
                     r2.x, r2.y, r2.z, r2.w, r3.x, r3.y, r3.z, r3.w };
    #pragma unroll
    for (int k = 0; k < 16; k++) {
      acc.x += wv[k] * tq[k].x; acc.y += wv[k] * tq[k].y;
      acc.z += wv[k] * tq[k].z; acc.w += wv[k] * tq[k].w;
    }
    *(float4*)(out0 + (size_t)p * 16 + q * 4) = acc;
  }
}

// out1: 8 lanes per pair, each owns a co-pair; thetas for both Y and Y^T hoisted
__global__ __launch_bounds__(256)
void k_out1(const float* __restrict__ y, const float* __restrict__ th1,
            const float* __restrict__ A1C, const float* __restrict__ B1,
            const float* __restrict__ DD1, float* __restrict__ out1) {
  int tid = blockIdx.x * 256 + threadIdx.x;
  int q = tid & 7;
  int slot = tid >> 3;
  int nslots = (gridDim.x * 256) >> 3;
  float2 tA[16], tB[16];
  #pragma unroll
  for (int k = 0; k < 16; k++) {
    tA[k] = *(const float2*)(th1 + 13 * 256 + k * 16 + q * 2);
    tB[k] = *(const float2*)(th1 + 11 * 256 + k * 16 + q * 2);
  }
  for (int p = slot; p < 512 * 512; p += nslots) {
    int a = p >> 9, b = p & 511;
    const float4* ra = (const float4*)(y + (size_t)p * 16);
    const float4* rt = (const float4*)(y + (size_t)((b << 9) | a) * 16);
    float4 a0 = ra[0], a1v = ra[1], a2 = ra[2], a3 = ra[3];
    float4 t0 = rt[0], t1v = rt[1], t2 = rt[2], t3 = rt[3];
    float2 acc = *(const float2*)(A1C + a * 16 + q * 2);
    float2 bb = *(const float2*)(B1 + b * 16 + q * 2);
    acc.x += bb.x; acc.y += bb.y;
    if (a == b) {
      float2 dd = *(const float2*)(DD1 + a * 16 + q * 2);
      acc.x += dd.x; acc.y += dd.y;
    }
    float ya[16] = { a0.x, a0.y, a0.z, a0.w, a1v.x, a1v.y, a1v.z, a1v.w,
                     a2.x, a2.y, a2.z, a2.w, a3.x, a3.y, a3.z, a3.w };
    float yt[16] = { t0.x, t0.y, t0.z, t0.w, t1v.x, t1v.y, t1v.z, t1v.w,
                     t2.x, t2.y, t2.z, t2.w, t3.x, t3.y, t3.z, t3.w };
    #pragma unroll
    for (int k = 0; k < 16; k++) {
      acc.x += ya[k] * tA[k].x + yt[k] * tB[k].x;
      acc.y += ya[k] * tA[k].y + yt[k] * tB[k].y;
    }
    *(float2*)(out1 + (size_t)p * 16 + q * 2) = acc;
  }
}

extern "C" void kernel_launch(void* const* d_in, const int* in_sizes, int n_in,
                              void* d_out, int out_size, void* d_ws, size_t ws_size,
                              hipStream_t stream) {
  const float* w_ih = (const float*)d_in[0];
  const float* w_hh = (const float*)d_in[1];
  const float* bvec = (const float*)d_in[2];
  const float *th0, *bias0, *th1, *bias1, *th2, *bias2;
  if (n_in >= 9 && in_sizes[4] == 16) {  // dict order: theta_0,bias_0,theta_1,bias_1,theta_2,bias_2
    th0 = (const float*)d_in[3]; bias0 = (const float*)d_in[4];
    th1 = (const float*)d_in[5]; bias1 = (const float*)d_in[6];
    th2 = (const float*)d_in[7]; bias2 = (const float*)d_in[8];
  } else {  // signature order: theta_0,theta_1,theta_2,bias_0,bias_1,bias_2
    th0 = (const float*)d_in[3]; th1 = (const float*)d_in[4]; th2 = (const float*)d_in[5];
    bias0 = (const float*)d_in[6]; bias1 = (const float*)d_in[7]; bias2 = (const float*)d_in[8];
  }
  float* ws    = (float*)d_ws;
  float* rm_ih = ws;               // 784*16
  float* cm_ih = rm_ih + 12544;    // 512*16
  float* rm_hh = cm_ih + 8192;
  float* cm_hh = rm_hh + 8192;
  float* d_hh  = cm_hh + 8192;
  float* A0C   = d_hh + 8192;      // 784*16
  float* B0    = A0C + 12544;
  float* A1C   = B0 + 8192;
  float* B1    = A1C + 8192;
  float* DD1   = B1 + 8192;
  float* sc    = DD1 + 8192;       // 64
  float* out0 = (float*)d_out;
  float* out1 = out0 + (size_t)784 * 512 * 16;
  float* out2 = out1 + (size_t)512 * 512 * 16;

  hipLaunchKernelGGL(k_rowmean_ih, dim3(784), dim3(256), 0, stream, w_ih, rm_ih);
  hipLaunchKernelGGL(k_colred, dim3(512), dim3(256), 0, stream, w_ih, w_hh, cm_ih, rm_hh, cm_hh, d_hh);
  hipLaunchKernelGGL(k_scalars, dim3(1), dim3(256), 0, stream, rm_ih, d_hh, rm_hh, bvec,
                     th0, bias0, th1, bias1, th2, bias2, sc);
  hipLaunchKernelGGL(k_vec, dim3(49), dim3(256), 0, stream, rm_ih, cm_ih, rm_hh, cm_hh, d_hh, bvec,
                     th0, th1, th2, sc, A0C, B0, A1C, B1, DD1, out2);
  hipLaunchKernelGGL(k_out0, dim3(1024), dim3(256), 0, stream, w_ih, th0, A0C, B0, out0);
  hipLaunchKernelGGL(k_out1, dim3(1024), dim3(256), 0, stream, w_hh, th1, A1C, B1, DD1, out1);
}

// Round 2
// 177.441 us; speedup vs baseline: 1.1920x; 1.1920x over previous
//
#include <hip/hip_runtime.h>

// NFLinear equivariant layer, closed-form decomposition.
// out0[a,b,:] = w_ih[a,b,:]@th0[0] + A0C[a,:] + B0[b,:]
// out1[a,b,:] = Y[a,b,:]@th1[13] + Y[b,a,:]@th1[11] + A1C[a,:] + B1[b,:] + (a==b)*DD1[a,:]
// out2[b,:]   = vectors(b)@th2 + scalars   (written by k_vec)
//
// 3-kernel pipeline: k_stage1 (row/col/diag means) -> k_vec (global means +
// scalar projections + per-row/col vectors + out2) -> k_out (both big streams).

#define N0 784
#define N1 512

// grid 1296: blocks [0,784) row-means of w_ih; [784,1296) col/row/diag reds.
__global__ __launch_bounds__(256)
void k_stage1(const float* __restrict__ wih, const float* __restrict__ whh,
              float* __restrict__ rm_ih, float* __restrict__ cm_ih,
              float* __restrict__ rm_hh, float* __restrict__ cm_hh,
              float* __restrict__ d_hh) {
  __shared__ float4 red[256];
  int t = threadIdx.x;
  if (blockIdx.x < N0) {
    // row-mean of w_ih row a: 8192 floats contiguous
    int a = blockIdx.x;
    const float4* row = (const float4*)(wih + (size_t)a * 8192);
    float4 acc = make_float4(0.f, 0.f, 0.f, 0.f);
    for (int j = t; j < 2048; j += 256) {
      float4 v = row[j];
      acc.x += v.x; acc.y += v.y; acc.z += v.z; acc.w += v.w;
    }
    red[t] = acc; __syncthreads();
    #pragma unroll
    for (int s = 128; s >= 4; s >>= 1) {
      if (t < s) {
        float4 o = red[t + s], m = red[t];
        m.x += o.x; m.y += o.y; m.z += o.z; m.w += o.w;
        red[t] = m;
      }
      __syncthreads();
    }
    if (t < 4) {
      float4 m = red[t];
      const float s = 1.0f / 512.0f;
      float4 o = make_float4(m.x * s, m.y * s, m.z * s, m.w * s);
      ((float4*)(rm_ih + a * 16))[t] = o;
    }
    return;
  }
  int b = blockIdx.x - N0;
  int q = t & 3, g = t >> 2;  // 64 row-groups, each lane owns a co-quad (float4)

  // cm_ih[b]: sum over a of w_ih[a,b,:]
  float4 acc = make_float4(0.f, 0.f, 0.f, 0.f);
  for (int a = g; a < N0; a += 64) {
    float4 v = *(const float4*)(wih + (size_t)a * 8192 + b * 16 + q * 4);
    acc.x += v.x; acc.y += v.y; acc.z += v.z; acc.w += v.w;
  }
  red[t] = acc; __syncthreads();
  #pragma unroll
  for (int s = 128; s >= 4; s >>= 1) {
    if (t < s) {
      float4 o = red[t + s], m = red[t];
      m.x += o.x; m.y += o.y; m.z += o.z; m.w += o.w;
      red[t] = m;
    }
    __syncthreads();
  }
  if (t < 4) {
    float4 m = red[t];
    const float s = 1.0f / 784.0f;
    ((float4*)(cm_ih + b * 16))[t] = make_float4(m.x * s, m.y * s, m.z * s, m.w * s);
  }
  __syncthreads();

  // rm_hh[b]: sum of row b of w_hh (8192 contiguous floats); chunk n has ci base (n&3)*4
  const float4* rowp = (const float4*)(whh + (size_t)b * 8192);
  acc = make_float4(0.f, 0.f, 0.f, 0.f);
  for (int n = t; n < 2048; n += 256) {  // (n&3) == (t&3) invariant
    float4 v = rowp[n];
    acc.x += v.x; acc.y += v.y; acc.z += v.z; acc.w += v.w;
  }
  red[t] = acc; __syncthreads();
  #pragma unroll
  for (int s = 128; s >= 4; s >>= 1) {
    if (t < s) {
      float4 o = red[t + s], m = red[t];
      m.x += o.x; m.y += o.y; m.z += o.z; m.w += o.w;
      red[t] = m;
    }
    __syncthreads();
  }
  if (t < 4) {
    float4 m = red[t];
    const float s = 1.0f / 512.0f;
    ((float4*)(rm_hh + b * 16))[t] = make_float4(m.x * s, m.y * s, m.z * s, m.w * s);
  }
  __syncthreads();

  // cm_hh[b]: sum over c of w_hh[c,b,:]
  acc = make_float4(0.f, 0.f, 0.f, 0.f);
  for (int a = g; a < N1; a += 64) {
    float4 v = *(const float4*)(whh + (size_t)a * 8192 + b * 16 + q * 4);
    acc.x += v.x; acc.y += v.y; acc.z += v.z; acc.w += v.w;
  }
  red[t] = acc; __syncthreads();
  #pragma unroll
  for (int s = 128; s >= 4; s >>= 1) {
    if (t < s) {
      float4 o = red[t + s], m = red[t];
      m.x += o.x; m.y += o.y; m.z += o.z; m.w += o.w;
      red[t] = m;
    }
    __syncthreads();
  }
  if (t < 4) {
    float4 m = red[t];
    const float s = 1.0f / 512.0f;
    ((float4*)(cm_hh + b * 16))[t] = make_float4(m.x * s, m.y * s, m.z * s, m.w * s);
    // diag
    ((float4*)(d_hh + b * 16))[t] = *(const float4*)(whh + (size_t)b * 8192 + b * 16 + t * 4);
  }
}

// grid 49: per block — global means + scalar projections (redundant, L2-hot)
// then per-(row,co) vectors A0C,B0,A1C,B1,DD1 and out2.
__global__ __launch_bounds__(256)
void k_vec(const float* __restrict__ rm_ih, const float* __restrict__ cm_ih,
           const float* __restrict__ rm_hh, const float* __restrict__ cm_hh,
           const float* __restrict__ d_hh, const float* __restrict__ bvec,
           const float* __restrict__ th0, const float* __restrict__ bias0,
           const float* __restrict__ th1, const float* __restrict__ bias1,
           const float* __restrict__ th2, const float* __restrict__ bias2,
           float* __restrict__ A0C, float* __restrict__ B0,
           float* __restrict__ A1C, float* __restrict__ B1,
           float* __restrict__ DD1, float* __restrict__ out2) {
  __shared__ float redf[256];
  __shared__ float4 red4[256];
  __shared__ float gv[4][16];
  __shared__ float sc[64];
  int t = threadIdx.x, ci = t & 15, g = t >> 4;

  // gv[0] = mean over a of rm_ih ; gv[1] = mean d_hh ; gv[2] = mean rm_hh ; gv[3] = mean b
  {
    float acc = 0.f;
    for (int a = g; a < N0; a += 16) acc += rm_ih[a * 16 + ci];
    redf[t] = acc; __syncthreads();
    for (int s = 128; s >= 16; s >>= 1) { if (t < s) redf[t] += redf[t + s]; __syncthreads(); }
    if (t < 16) gv[0][t] = redf[t] * (1.0f / 784.0f);
    __syncthreads();
    acc = 0.f;
    for (int a = g; a < N1; a += 16) acc += d_hh[a * 16 + ci];
    redf[t] = acc; __syncthreads();
    for (int s = 128; s >= 16; s >>= 1) { if (t < s) redf[t] += redf[t + s]; __syncthreads(); }
    if (t < 16) gv[1][t] = redf[t] * (1.0f / 512.0f);
    __syncthreads();
    acc = 0.f;
    for (int a = g; a < N1; a += 16) acc += rm_hh[a * 16 + ci];
    redf[t] = acc; __syncthreads();
    for (int s = 128; s >= 16; s >>= 1) { if (t < s) redf[t] += redf[t + s]; __syncthreads(); }
    if (t < 16) gv[2][t] = redf[t] * (1.0f / 512.0f);
    __syncthreads();
    acc = 0.f;
    for (int a = g; a < N1; a += 16) acc += bvec[a * 16 + ci];
    redf[t] = acc; __syncthreads();
    for (int s = 128; s >= 16; s >>= 1) { if (t < s) redf[t] += redf[t + s]; __syncthreads(); }
    if (t < 16) gv[3][t] = redf[t] * (1.0f / 512.0f);
    __syncthreads();
  }
  // scalar projections: thread (co = t&15, j = t>>4) partial over k=j, reduce over j
  {
    int co = ci, j = g, o = j * 16 + co;
    float g0 = gv[0][j], dm = gv[1][j], gh = gv[2][j], mv = gv[3][j];
    float4 p;
    p.x = g0 * th0[768 + o]  + dm * th0[1280 + o] + gh * th0[2048 + o] + mv * th0[2560 + o];  // C0
    p.y = g0 * th1[1024 + o] + dm * th1[2304 + o] + gh * th1[4864 + o] + mv * th1[6144 + o];  // C1
    p.z = g0 * th1[512 + o]  + dm * th1[1792 + o] + gh * th1[4096 + o] + mv * th1[5632 + o];  // E1
    p.w = g0 * th2[256 + o]  + dm * th2[768 + o]  + gh * th2[1536 + o] + mv * th2[2048 + o];  // S2
    red4[t] = p; __syncthreads();
    for (int s = 128; s >= 16; s >>= 1) {
      if (t < s) {
        float4 a = red4[t], b = red4[t + s];
        a.x += b.x; a.y += b.y; a.z += b.z; a.w += b.w;
        red4[t] = a;
      }
      __syncthreads();
    }
    if (t < 16) {
      float4 a = red4[t];
      sc[t] = a.x + bias0[t];
      sc[16 + t] = a.y + bias1[t];
      sc[32 + t] = a.z + bias2[t] * 0.f + 0.f;  // E1 has no bias
      sc[32 + t] = a.z;
      sc[48 + t] = a.w + bias2[t];
    }
    __syncthreads();
  }
  // vector terms
  int idx = blockIdx.x * 256 + t;
  int i = idx >> 4, co = idx & 15;
  if (i >= N0) return;
  float a0 = sc[co];
  for (int k = 0; k < 16; k++) a0 += rm_ih[i * 16 + k] * th0[256 + k * 16 + co];
  A0C[idx] = a0;
  if (i < N1) {
    float b0a = 0.f, a1 = sc[16 + co], b1a = 0.f, dd = sc[32 + co], o2 = sc[48 + co];
    for (int k = 0; k < 16; k++) {
      float cmi = cm_ih[i * 16 + k], d = d_hh[i * 16 + k], r = rm_hh[i * 16 + k];
      float cm = cm_hh[i * 16 + k], v = bvec[i * 16 + k];
      int o = k * 16 + co;
      b0a += cmi * th0[512 + o]  + d * th0[1024 + o] + r * th0[1536 + o] + cm * th0[1792 + o] + v * th0[2304 + o];
      a1  += cmi * th1[768 + o]  + d * th1[2048 + o] + r * th1[4352 + o] + cm * th1[4608 + o] + v * th1[5888 + o];
      b1a += cmi * th1[256 + o]  + d * th1[1536 + o] + r * th1[3072 + o] + cm * th1[3840 + o] + v * th1[5376 + o];
      dd  += cmi * th1[0 + o]    + d * th1[1280 + o] + r * th1[2560 + o] + cm * th1[3584 + o] + v * th1[5120 + o];
      o2  += cmi * th2[0 + o]    + d * th2[512 + o]  + r * th2[1024 + o] + cm * th2[1280 + o] + v * th2[1792 + o];
    }
    B0[idx] = b0a; A1C[idx] = a1; B1[idx] = b1a; DD1[idx] = dd; out2[idx] = o2;
  }
}

// grid 2048: blocks [0,1024) stream out0; [1024,2048) stream out1.
__global__ __launch_bounds__(256)
void k_out(const float* __restrict__ wih, const float* __restrict__ whh,
           const float* __restrict__ th0, const float* __restrict__ th1,
           const float* __restrict__ A0C, const float* __restrict__ B0,
           const float* __restrict__ A1C, const float* __restrict__ B1,
           const float* __restrict__ DD1,
           float* __restrict__ out0, float* __restrict__ out1) {
  if (blockIdx.x < 1024) {
    int tid = blockIdx.x * 256 + threadIdx.x;
    int q = tid & 3;
    int slot = tid >> 2;
    const int nslots = (1024 * 256) >> 2;
    float4 tq[16];
    #pragma unroll
    for (int k = 0; k < 16; k++) tq[k] = *(const float4*)(th0 + k * 16 + q * 4);
    for (int p = slot; p < N0 * N1; p += nslots) {
      const float4* row = (const float4*)(wih + (size_t)p * 16);
      float4 r0 = row[0], r1 = row[1], r2 = row[2], r3 = row[3];
      int a = p >> 9, bb = p & 511;
      float4 acc = *(const float4*)(A0C + a * 16 + q * 4);
      float4 b4 = *(const float4*)(B0 + bb * 16 + q * 4);
      acc.x += b4.x; acc.y += b4.y; acc.z += b4.z; acc.w += b4.w;
      float wv[16] = { r0.x, r0.y, r0.z, r0.w, r1.x, r1.y, r1.z, r1.w,
                       r2.x, r2.y, r2.z, r2.w, r3.x, r3.y, r3.z, r3.w };
      #pragma unroll
      for (int k = 0; k < 16; k++) {
        acc.x += wv[k] * tq[k].x; acc.y += wv[k] * tq[k].y;
        acc.z += wv[k] * tq[k].z; acc.w += wv[k] * tq[k].w;
      }
      *(float4*)(out0 + (size_t)p * 16 + q * 4) = acc;
    }
  } else {
    int tid = (blockIdx.x - 1024) * 256 + threadIdx.x;
    int q = tid & 7;
    int slot = tid >> 3;
    const int nslots = (1024 * 256) >> 3;
    float2 tA[16], tB[16];
    #pragma unroll
    for (int k = 0; k < 16; k++) {
      tA[k] = *(const float2*)(th1 + 13 * 256 + k * 16 + q * 2);
      tB[k] = *(const float2*)(th1 + 11 * 256 + k * 16 + q * 2);
    }
    for (int p = slot; p < N1 * N1; p += nslots) {
      int a = p >> 9, b = p & 511;
      const float4* ra = (const float4*)(whh + (size_t)p * 16);
      const float4* rt = (const float4*)(whh + (size_t)((b << 9) | a) * 16);
      float4 a0 = ra[0], a1v = ra[1], a2 = ra[2], a3 = ra[3];
      float4 t0 = rt[0], t1v = rt[1], t2 = rt[2], t3 = rt[3];
      float2 acc = *(const float2*)(A1C + a * 16 + q * 2);
      float2 bb = *(const float2*)(B1 + b * 16 + q * 2);
      acc.x += bb.x; acc.y += bb.y;
      if (a == b) {
        float2 dd = *(const float2*)(DD1 + a * 16 + q * 2);
        acc.x += dd.x; acc.y += dd.y;
      }
      float ya[16] = { a0.x, a0.y, a0.z, a0.w, a1v.x, a1v.y, a1v.z, a1v.w,
                       a2.x, a2.y, a2.z, a2.w, a3.x, a3.y, a3.z, a3.w };
      float yt[16] = { t0.x, t0.y, t0.z, t0.w, t1v.x, t1v.y, t1v.z, t1v.w,
                       t2.x, t2.y, t2.z, t2.w, t3.x, t3.y, t3.z, t3.w };
      #pragma unroll
      for (int k = 0; k < 16; k++) {
        acc.x += ya[k] * tA[k].x + yt[k] * tB[k].x;
        acc.y += ya[k] * tA[k].y + yt[k] * tB[k].y;
      }
      *(float2*)(out1 + (size_t)p * 16 + q * 2) = acc;
    }
  }
}

extern "C" void kernel_launch(void* const* d_in, const int* in_sizes, int n_in,
                              void* d_out, int out_size, void* d_ws, size_t ws_size,
                              hipStream_t stream) {
  const float* w_ih = (const float*)d_in[0];
  const float* w_hh = (const float*)d_in[1];
  const float* bvec = (const float*)d_in[2];
  const float *th0, *bias0, *th1, *bias1, *th2, *bias2;
  if (n_in >= 9 && in_sizes[4] == 16) {  // dict order: theta_0,bias_0,theta_1,bias_1,theta_2,bias_2
    th0 = (const float*)d_in[3]; bias0 = (const float*)d_in[4];
    th1 = (const float*)d_in[5]; bias1 = (const float*)d_in[6];
    th2 = (const float*)d_in[7]; bias2 = (const float*)d_in[8];
  } else {  // signature order
    th0 = (const float*)d_in[3]; th1 = (const float*)d_in[4]; th2 = (const float*)d_in[5];
    bias0 = (const float*)d_in[6]; bias1 = (const float*)d_in[7]; bias2 = (const float*)d_in[8];
  }
  float* ws    = (float*)d_ws;
  float* rm_ih = ws;               // 784*16
  float* cm_ih = rm_ih + 12544;    // 512*16
  float* rm_hh = cm_ih + 8192;
  float* cm_hh = rm_hh + 8192;
  float* d_hh  = cm_hh + 8192;
  float* A0C   = d_hh + 8192;      // 784*16
  float* B0    = A0C + 12544;
  float* A1C   = B0 + 8192;
  float* B1    = A1C + 8192;
  float* DD1   = B1 + 8192;
  float* out0 = (float*)d_out;
  float* out1 = out0 + (size_t)N0 * N1 * 16;
  float* out2 = out1 + (size_t)N1 * N1 * 16;

  hipLaunchKernelGGL(k_stage1, dim3(N0 + N1), dim3(256), 0, stream,
                     w_ih, w_hh, rm_ih, cm_ih, rm_hh, cm_hh, d_hh);
  hipLaunchKernelGGL(k_vec, dim3(49), dim3(256), 0, stream,
                     rm_ih, cm_ih, rm_hh, cm_hh, d_hh, bvec,
                     th0, bias0, th1, bias1, th2, bias2,
                     A0C, B0, A1C, B1, DD1, out2);
  hipLaunchKernelGGL(k_out, dim3(2048), dim3(256), 0, stream,
                     w_ih, w_hh, th0, th1, A0C, B0, A1C, B1, DD1, out0, out1);
}

// Round 3
// 153.619 us; speedup vs baseline: 1.3768x; 1.1551x over previous
//
#include <hip/hip_runtime.h>

// NFLinear equivariant layer, closed-form decomposition.
// out0[a,b,:] = w_ih[a,b,:]@th0[0] + A0C[a,:] + B0[b,:]
// out1[a,b,:] = Y[a,b,:]@th1[13] + Y[b,a,:]@th1[11] + A1C[a,:] + B1[b,:] + (a==b)*DD1[a,:]
// out2[b,:]   = vectors(b)@th2 + scalars   (written by k_vec)

#define N0 784
#define N1 512

__device__ __forceinline__ float4 f4add(float4 a, float4 b) {
  a.x += b.x; a.y += b.y; a.z += b.z; a.w += b.w; return a;
}

// grid 2320, one reduction phase per block:
// [0,784): row-mean w_ih -> rm_ih ; [784,1296): col-mean w_ih -> cm_ih
// [1296,1808): row-mean w_hh -> rm_hh ; [1808,2320): col-mean w_hh -> cm_hh + diag
__global__ __launch_bounds__(256)
void k_stage1(const float* __restrict__ wih, const float* __restrict__ whh,
              float* __restrict__ rm_ih, float* __restrict__ cm_ih,
              float* __restrict__ rm_hh, float* __restrict__ cm_hh,
              float* __restrict__ d_hh) {
  __shared__ float4 red[256];
  int t = threadIdx.x, blk = blockIdx.x;
  float4 acc = make_float4(0.f, 0.f, 0.f, 0.f);
  float scale;
  float* dst;
  if (blk < N0) {
    const float4* row = (const float4*)(wih + (size_t)blk * 8192);
    for (int j = t; j < 2048; j += 256) acc = f4add(acc, row[j]);
    scale = 1.f / 512.f; dst = rm_ih + blk * 16;
  } else if (blk < N0 + N1) {
    int b = blk - N0, q = t & 3, g = t >> 2;
    for (int a = g; a < N0; a += 64)
      acc = f4add(acc, *(const float4*)(wih + (size_t)a * 8192 + b * 16 + q * 4));
    scale = 1.f / 784.f; dst = cm_ih + b * 16;
  } else if (blk < N0 + 2 * N1) {
    int b = blk - N0 - N1;
    const float4* row = (const float4*)(whh + (size_t)b * 8192);
    for (int j = t; j < 2048; j += 256) acc = f4add(acc, row[j]);
    scale = 1.f / 512.f; dst = rm_hh + b * 16;
  } else {
    int b = blk - N0 - 2 * N1, q = t & 3, g = t >> 2;
    for (int a = g; a < N1; a += 64)
      acc = f4add(acc, *(const float4*)(whh + (size_t)a * 8192 + b * 16 + q * 4));
    scale = 1.f / 512.f; dst = cm_hh + b * 16;
    if (t < 4) ((float4*)(d_hh + b * 16))[t] = *(const float4*)(whh + (size_t)b * 8192 + b * 16 + t * 4);
  }
  red[t] = acc; __syncthreads();
  #pragma unroll
  for (int s = 128; s >= 4; s >>= 1) {
    if (t < s) red[t] = f4add(red[t], red[t + s]);
    __syncthreads();
  }
  if (t < 4) {  // red[t] = sum over lanes == t (mod 4) -> quad t of the 16-vector
    float4 m = red[t];
    ((float4*)dst)[t] = make_float4(m.x * scale, m.y * scale, m.z * scale, m.w * scale);
  }
}

// grid 49: thetas staged in LDS; global means via float4 tree reductions
// (redundant per block, L2/L3-hot); scalar projections; vector terms; out2.
__global__ __launch_bounds__(256)
void k_vec(const float* __restrict__ rm_ih, const float* __restrict__ cm_ih,
           const float* __restrict__ rm_hh, const float* __restrict__ cm_hh,
           const float* __restrict__ d_hh, const float* __restrict__ bvec,
           const float* __restrict__ th0, const float* __restrict__ bias0,
           const float* __restrict__ th1, const float* __restrict__ bias1,
           const float* __restrict__ th2, const float* __restrict__ bias2,
           float* __restrict__ A0C, float* __restrict__ B0,
           float* __restrict__ A1C, float* __restrict__ B1,
           float* __restrict__ DD1, float* __restrict__ out2) {
  __shared__ float th[11520];   // th0 @0 (2816), th1 @2816 (6400), th2 @9216 (2304)
  __shared__ float4 red[256];
  __shared__ float gv[4][16];
  __shared__ float sc[64];
  int t = threadIdx.x;
  {
    float4* t4 = (float4*)th;
    const float4* s0 = (const float4*)th0;
    const float4* s1 = (const float4*)th1;
    const float4* s2 = (const float4*)th2;
    for (int j = t; j < 704; j += 256) t4[j] = s0[j];
    for (int j = t; j < 1600; j += 256) t4[704 + j] = s1[j];
    for (int j = t; j < 576; j += 256) t4[2304 + j] = s2[j];
  }
  int q = t & 3, g = t >> 2;
  // gv[0]=mean rm_ih, gv[1]=mean d_hh, gv[2]=mean rm_hh, gv[3]=mean bvec
  {
    float4 acc = make_float4(0.f, 0.f, 0.f, 0.f);
    for (int a = g; a < N0; a += 64) acc = f4add(acc, ((const float4*)rm_ih)[a * 4 + q]);
    red[t] = acc; __syncthreads();
    #pragma unroll
    for (int s = 128; s >= 4; s >>= 1) { if (t < s) red[t] = f4add(red[t], red[t + s]); __syncthreads(); }
    if (t < 4) {
      float4 m = red[t];
      gv[0][t * 4 + 0] = m.x / 784.f; gv[0][t * 4 + 1] = m.y / 784.f;
      gv[0][t * 4 + 2] = m.z / 784.f; gv[0][t * 4 + 3] = m.w / 784.f;
    }
    __syncthreads();
  }
  const float* srcs[3] = { d_hh, rm_hh, bvec };
  #pragma unroll
  for (int v = 0; v < 3; v++) {
    float4 acc = make_float4(0.f, 0.f, 0.f, 0.f);
    for (int a = g; a < N1; a += 64) acc = f4add(acc, ((const float4*)srcs[v])[a * 4 + q]);
    red[t] = acc; __syncthreads();
    #pragma unroll
    for (int s = 128; s >= 4; s >>= 1) { if (t < s) red[t] = f4add(red[t], red[t + s]); __syncthreads(); }
    if (t < 4) {
      float4 m = red[t];
      gv[v + 1][t * 4 + 0] = m.x / 512.f; gv[v + 1][t * 4 + 1] = m.y / 512.f;
      gv[v + 1][t * 4 + 2] = m.z / 512.f; gv[v + 1][t * 4 + 3] = m.w / 512.f;
    }
    __syncthreads();
  }
  // scalar projections: C0, C1, E1, S2
  {
    int co = t & 15, j = t >> 4, o = j * 16 + co;
    float g0v = gv[0][j], dm = gv[1][j], gh = gv[2][j], mv = gv[3][j];
    float4 p;
    p.x = g0v * th[768 + o]         + dm * th[1280 + o]        + gh * th[2048 + o]        + mv * th[2560 + o];
    p.y = g0v * th[2816 + 1024 + o] + dm * th[2816 + 2304 + o] + gh * th[2816 + 4864 + o] + mv * th[2816 + 6144 + o];
    p.z = g0v * th[2816 + 512 + o]  + dm * th[2816 + 1792 + o] + gh * th[2816 + 4096 + o] + mv * th[2816 + 5632 + o];
    p.w = g0v * th[9216 + 256 + o]  + dm * th[9216 + 768 + o]  + gh * th[9216 + 1536 + o] + mv * th[9216 + 2048 + o];
    red[t] = p; __syncthreads();
    #pragma unroll
    for (int s = 128; s >= 16; s >>= 1) { if (t < s) red[t] = f4add(red[t], red[t + s]); __syncthreads(); }
    if (t < 16) {
      float4 a = red[t];
      sc[t] = a.x + bias0[t];
      sc[16 + t] = a.y + bias1[t];
      sc[32 + t] = a.z;              // E1: no bias
      sc[48 + t] = a.w + bias2[t];
    }
    __syncthreads();
  }
  // vector terms
  int idx = blockIdx.x * 256 + t;
  int i = idx >> 4, co = idx & 15;
  float a0 = sc[co];
  {
    const float4* r4 = (const float4*)(rm_ih + i * 16);
    #pragma unroll
    for (int kq = 0; kq < 4; kq++) {
      float4 r = r4[kq];
      float vr[4] = { r.x, r.y, r.z, r.w };
      #pragma unroll
      for (int e = 0; e < 4; e++) a0 += vr[e] * th[256 + (kq * 4 + e) * 16 + co];
    }
  }
  A0C[idx] = a0;
  if (i < N1) {
    float b0a = 0.f, a1 = sc[16 + co], b1a = 0.f, dd = sc[32 + co], o2 = sc[48 + co];
    const float4* c4 = (const float4*)(cm_ih + i * 16);
    const float4* d4 = (const float4*)(d_hh + i * 16);
    const float4* r4 = (const float4*)(rm_hh + i * 16);
    const float4* m4 = (const float4*)(cm_hh + i * 16);
    const float4* v4 = (const float4*)(bvec + i * 16);
    #pragma unroll
    for (int kq = 0; kq < 4; kq++) {
      float4 cq = c4[kq], dq = d4[kq], rq = r4[kq], mq = m4[kq], vq = v4[kq];
      float vc[4] = { cq.x, cq.y, cq.z, cq.w };
      float vd[4] = { dq.x, dq.y, dq.z, dq.w };
      float vr[4] = { rq.x, rq.y, rq.z, rq.w };
      float vm[4] = { mq.x, mq.y, mq.z, mq.w };
      float vb[4] = { vq.x, vq.y, vq.z, vq.w };
      #pragma unroll
      for (int e = 0; e < 4; e++) {
        int o = (kq * 4 + e) * 16 + co;
        float cmi = vc[e], d = vd[e], r = vr[e], cm = vm[e], v = vb[e];
        b0a += cmi * th[512 + o]         + d * th[1024 + o]        + r * th[1536 + o]        + cm * th[1792 + o]        + v * th[2304 + o];
        a1  += cmi * th[2816 + 768 + o]  + d * th[2816 + 2048 + o] + r * th[2816 + 4352 + o] + cm * th[2816 + 4608 + o] + v * th[2816 + 5888 + o];
        b1a += cmi * th[2816 + 256 + o]  + d * th[2816 + 1536 + o] + r * th[2816 + 3072 + o] + cm * th[2816 + 3840 + o] + v * th[2816 + 5376 + o];
        dd  += cmi * th[2816 + 0 + o]    + d * th[2816 + 1280 + o] + r * th[2816 + 2560 + o] + cm * th[2816 + 3584 + o] + v * th[2816 + 5120 + o];
        o2  += cmi * th[9216 + 0 + o]    + d * th[9216 + 512 + o]  + r * th[9216 + 1024 + o] + cm * th[9216 + 1280 + o] + v * th[9216 + 1792 + o];
      }
    }
    B0[idx] = b0a; A1C[idx] = a1; B1[idx] = b1a; DD1[idx] = dd; out2[idx] = o2;
  }
}

// grid 2048: blocks [0,1024) stream out0; [1024,2048) stream out1.
__global__ __launch_bounds__(256)
void k_out(const float* __restrict__ wih, const float* __restrict__ whh,
           const float* __restrict__ th0, const float* __restrict__ th1,
           const float* __restrict__ A0C, const float* __restrict__ B0,
           const float* __restrict__ A1C, const float* __restrict__ B1,
           const float* __restrict__ DD1,
           float* __restrict__ out0, float* __restrict__ out1) {
  if (blockIdx.x < 1024) {
    int tid = blockIdx.x * 256 + threadIdx.x;
    int q = tid & 3;
    int slot = tid >> 2;
    const int nslots = (1024 * 256) >> 2;
    float4 tq[16];
    #pragma unroll
    for (int k = 0; k < 16; k++) tq[k] = *(const float4*)(th0 + k * 16 + q * 4);
    for (int p = slot; p < N0 * N1; p += nslots) {
      const float4* row = (const float4*)(wih + (size_t)p * 16);
      float4 r0 = row[0], r1 = row[1], r2 = row[2], r3 = row[3];
      int a = p >> 9, bb = p & 511;
      float4 acc = *(const float4*)(A0C + a * 16 + q * 4);
      float4 b4 = *(const float4*)(B0 + bb * 16 + q * 4);
      acc.x += b4.x; acc.y += b4.y; acc.z += b4.z; acc.w += b4.w;
      float wv[16] = { r0.x, r0.y, r0.z, r0.w, r1.x, r1.y, r1.z, r1.w,
                       r2.x, r2.y, r2.z, r2.w, r3.x, r3.y, r3.z, r3.w };
      #pragma unroll
      for (int k = 0; k < 16; k++) {
        acc.x += wv[k] * tq[k].x; acc.y += wv[k] * tq[k].y;
        acc.z += wv[k] * tq[k].z; acc.w += wv[k] * tq[k].w;
      }
      *(float4*)(out0 + (size_t)p * 16 + q * 4) = acc;
    }
  } else {
    int tid = (blockIdx.x - 1024) * 256 + threadIdx.x;
    int q = tid & 7;
    int slot = tid >> 3;
    const int nslots = (1024 * 256) >> 3;
    float2 tA[16], tB[16];
    #pragma unroll
    for (int k = 0; k < 16; k++) {
      tA[k] = *(const float2*)(th1 + 13 * 256 + k * 16 + q * 2);
      tB[k] = *(const float2*)(th1 + 11 * 256 + k * 16 + q * 2);
    }
    for (int p = slot; p < N1 * N1; p += nslots) {
      int a = p >> 9, b = p & 511;
      const float4* ra = (const float4*)(whh + (size_t)p * 16);
      const float4* rt = (const float4*)(whh + (size_t)((b << 9) | a) * 16);
      float4 a0 = ra[0], a1v = ra[1], a2 = ra[2], a3 = ra[3];
      float4 t0 = rt[0], t1v = rt[1], t2 = rt[2], t3 = rt[3];
      float2 acc = *(const float2*)(A1C + a * 16 + q * 2);
      float2 bb = *(const float2*)(B1 + b * 16 + q * 2);
      acc.x += bb.x; acc.y += bb.y;
      if (a == b) {
        float2 dd = *(const float2*)(DD1 + a * 16 + q * 2);
        acc.x += dd.x; acc.y += dd.y;
      }
      float ya[16] = { a0.x, a0.y, a0.z, a0.w, a1v.x, a1v.y, a1v.z, a1v.w,
                       a2.x, a2.y, a2.z, a2.w, a3.x, a3.y, a3.z, a3.w };
      float yt[16] = { t0.x, t0.y, t0.z, t0.w, t1v.x, t1v.y, t1v.z, t1v.w,
                       t2.x, t2.y, t2.z, t2.w, t3.x, t3.y, t3.z, t3.w };
      #pragma unroll
      for (int k = 0; k < 16; k++) {
        acc.x += ya[k] * tA[k].x + yt[k] * tB[k].x;
        acc.y += ya[k] * tA[k].y + yt[k] * tB[k].y;
      }
      *(float2*)(out1 + (size_t)p * 16 + q * 2) = acc;
    }
  }
}

extern "C" void kernel_launch(void* const* d_in, const int* in_sizes, int n_in,
                              void* d_out, int out_size, void* d_ws, size_t ws_size,
                              hipStream_t stream) {
  const float* w_ih = (const float*)d_in[0];
  const float* w_hh = (const float*)d_in[1];
  const float* bvec = (const float*)d_in[2];
  const float *th0, *bias0, *th1, *bias1, *th2, *bias2;
  if (n_in >= 9 && in_sizes[4] == 16) {  // dict order
    th0 = (const float*)d_in[3]; bias0 = (const float*)d_in[4];
    th1 = (const float*)d_in[5]; bias1 = (const float*)d_in[6];
    th2 = (const float*)d_in[7]; bias2 = (const float*)d_in[8];
  } else {  // signature order
    th0 = (const float*)d_in[3]; th1 = (const float*)d_in[4]; th2 = (const float*)d_in[5];
    bias0 = (const float*)d_in[6]; bias1 = (const float*)d_in[7]; bias2 = (const float*)d_in[8];
  }
  float* ws    = (float*)d_ws;
  float* rm_ih = ws;               // 784*16
  float* cm_ih = rm_ih + 12544;    // 512*16
  float* rm_hh = cm_ih + 8192;
  float* cm_hh = rm_hh + 8192;
  float* d_hh  = cm_hh + 8192;
  float* A0C   = d_hh + 8192;      // 784*16
  float* B0    = A0C + 12544;
  float* A1C   = B0 + 8192;
  float* B1    = A1C + 8192;
  float* DD1   = B1 + 8192;
  float* out0 = (float*)d_out;
  float* out1 = out0 + (size_t)N0 * N1 * 16;
  float* out2 = out1 + (size_t)N1 * N1 * 16;

  hipLaunchKernelGGL(k_stage1, dim3(N0 + 3 * N1), dim3(256), 0, stream,
                     w_ih, w_hh, rm_ih, cm_ih, rm_hh, cm_hh, d_hh);
  hipLaunchKernelGGL(k_vec, dim3(49), dim3(256), 0, stream,
                     rm_ih, cm_ih, rm_hh, cm_hh, d_hh, bvec,
                     th0, bias0, th1, bias1, th2, bias2,
                     A0C, B0, A1C, B1, DD1, out2);
  hipLaunchKernelGGL(k_out, dim3(2048), dim3(256), 0, stream,
                     w_ih, w_hh, th0, th1, A0C, B0, A1C, B1, DD1, out0, out1);
}